// Round 13
// baseline (625.262 us; speedup 1.0000x reference)
//
#include <hip/hip_runtime.h>
#include <stdint.h>
#include <utility>
#include <type_traits>

// ---------------- types / helpers ----------------
using bf16x8 = __attribute__((ext_vector_type(8))) short;   // 8 x bf16 (4 VGPRs)
using f32x4  = __attribute__((ext_vector_type(4))) float;
using u32x4  = __attribute__((ext_vector_type(4))) unsigned;

__device__ __forceinline__ f32x4 mfma16(bf16x8 a, bf16x8 b, f32x4 c) {
  return __builtin_amdgcn_mfma_f32_16x16x32_bf16(a, b, c, 0, 0, 0);
}

__device__ __forceinline__ unsigned short f2b_rne(float f) {
  union { float f; unsigned u; } v; v.f = f;
  unsigned r = v.u + 0x7fffu + ((v.u >> 16) & 1u);
  return (unsigned short)(r >> 16);
}

__device__ __forceinline__ void gload16(const void* g, void* l) {
  __builtin_amdgcn_global_load_lds(
      (const __attribute__((address_space(1))) void*)g,
      (__attribute__((address_space(3))) void*)l, 16, 0, 0);
}

template<int N> __device__ __forceinline__ void vmwait() {
  if constexpr (N <= 0)      asm volatile("s_waitcnt vmcnt(0)" ::: "memory");
  else if constexpr (N == 4) asm volatile("s_waitcnt vmcnt(4)" ::: "memory");
  else                       asm volatile("s_waitcnt vmcnt(8)" ::: "memory");
}

template<class F, int... Is>
__device__ __forceinline__ void sfor_impl(F&& f, std::integer_sequence<int, Is...>) {
  (f(std::integral_constant<int, Is>{}), ...);
}
template<int N, class F>
__device__ __forceinline__ void sfor(F&& f) {
  sfor_impl(static_cast<F&&>(f), std::make_integer_sequence<int, N>{});
}

// Stage one 16-col x 128-k tile (4 KB) of W[cols][K] into a wave-private LDS slot.
__device__ __forceinline__ void stage_tile(const unsigned short* __restrict__ W, int K,
                                           int col0, int kt, char* slot, int lane) {
#pragma unroll
  for (int i = 0; i < 4; ++i) {
    const int chunk = i * 64 + lane;
    const int ci = chunk >> 4, kc = chunk & 15;
    const unsigned short* src = W + (size_t)(col0 + ci) * K + kt * 128
                                + (((kc * 16) ^ ((ci & 7) << 4)) >> 1);
    gload16(src, slot + i * 1024);   // lane's 16B lands at slot + i*1024 + lane*16
  }
}

// Per-wave pipelined GEMM (R6-exact): acc[cg] += A[16 x K] @ W[(c0..c0+NCG*16) x K]^T
// A in LDS (row stride AS bytes, XOR-swizzled); W streamed via LDS ring (3 x 4KB,
// wave-private), 2 tiles in flight, steady-state vmcnt(4).
template<int NCG, int NKT, int AS, int K>
__device__ __forceinline__ void gemm_pipe(const unsigned short* __restrict__ W, int c0,
                                          const char* __restrict__ abuf,
                                          char* __restrict__ ring, int lane,
                                          f32x4 (&acc)[NCG]) {
  const int r = lane & 15, hi16 = (lane >> 4) << 4;
  const int swz = (r & 7) << 4;
  constexpr int TILES = NCG * NKT;   // tile t = (kt, cg) = (t / NCG, t % NCG)
  stage_tile(W, K, c0, 0, ring, lane);
  if constexpr (TILES > 1)
    stage_tile(W, K, c0 + (1 % NCG) * 16, 1 / NCG, ring + 4096, lane);
  bf16x8 areg[4];
  sfor<TILES>([&](auto tc) {
    constexpr int t = tc.value;
    constexpr int kt = t / NCG, cg = t % NCG;
    vmwait<((t + 2 <= TILES) ? 4 : 0)>();
    __builtin_amdgcn_sched_barrier(0);
    if constexpr (t + 2 < TILES) {
      constexpr int t2 = t + 2;
      stage_tile(W, K, c0 + (t2 % NCG) * 16, t2 / NCG, ring + (t2 % 3) * 4096, lane);
    }
    const char* slot = ring + (t % 3) * 4096;
#pragma unroll
    for (int ksl = 0; ksl < 4; ++ksl) {
      if constexpr (cg == 0)
        areg[ksl] = *reinterpret_cast<const bf16x8*>(
            abuf + r * AS + ((kt * 256 + ksl * 64 + hi16) ^ swz));
      const bf16x8 b = *reinterpret_cast<const bf16x8*>(
          slot + r * 256 + ((ksl * 64 + hi16) ^ swz));
      acc[cg] = mfma16(areg[ksl], b, acc[cg]);
    }
  });
}

// ---------------- fp32 -> bf16 conversion ----------------
__global__ void f2b_kernel(const float* __restrict__ s, unsigned short* __restrict__ d, int n4) {
  int i = blockIdx.x * 256 + threadIdx.x;
  if (i >= n4) return;
  float4 v = reinterpret_cast<const float4*>(s)[i];
  ushort4 o;
  o.x = f2b_rne(v.x); o.y = f2b_rne(v.y); o.z = f2b_rne(v.z); o.w = f2b_rne(v.w);
  reinterpret_cast<ushort4*>(d)[i] = o;
}

// ---------------- attn/cross weight composition (fp32): W_eff = Wo @ Wv, b_eff = Wo @ bv + bo ----
__global__ __launch_bounds__(256) void compose_attn(
    const float* __restrict__ aiW, const float* __restrict__ aib,
    const float* __restrict__ aoW, const float* __restrict__ aob,
    const float* __restrict__ ciW, const float* __restrict__ cib,
    const float* __restrict__ coW, const float* __restrict__ cob,
    unsigned short* __restrict__ wEff, float* __restrict__ bEff) {
  const int mat = blockIdx.y;
  const float* Wo = (mat < 6) ? aoW + (size_t)mat * 65536 : coW;
  const float* Wv = (mat < 6) ? aiW + (size_t)mat * 196608 + 131072 : ciW + 131072;
  const float* bv = (mat < 6) ? aib + mat * 768 + 512 : cib + 512;
  const float* bo = (mat < 6) ? aob + mat * 256 : cob;
  unsigned short* Wd = wEff + (size_t)mat * 65536;
  const int m = blockIdx.x * 16 + (threadIdx.x >> 4);
  const int k0 = (threadIdx.x & 15) * 16;
  float c[16] = {};
  for (int j = 0; j < 256; ++j) {
    const float a = Wo[m * 256 + j];
    const float* Br = Wv + j * 256 + k0;
#pragma unroll
    for (int kk = 0; kk < 16; ++kk) c[kk] = fmaf(a, Br[kk], c[kk]);
  }
#pragma unroll
  for (int kk = 0; kk < 16; ++kk) Wd[m * 256 + k0 + kk] = f2b_rne(c[kk]);
  if (blockIdx.x == 0) {
    const int mm = threadIdx.x;
    float s = 0.f;
    for (int j = 0; j < 256; ++j) s = fmaf(Wo[mm * 256 + j], bv[j], s);
    bEff[mat * 256 + mm] = s + bo[mm];
  }
}

// ---------------- fused trunk (R6-exact): 8 waves, 3x4KB LDS W-rings ----------------
__global__ __launch_bounds__(512, 2) void trunk_fused(
    const unsigned short* __restrict__ xb, const unsigned short* __restrict__ pWb,
    const float* __restrict__ projb,
    const unsigned short* __restrict__ wEff, const float* __restrict__ bEff,
    const unsigned short* __restrict__ f1Wb, const float* __restrict__ f1b,
    const unsigned short* __restrict__ f2Wb, const float* __restrict__ f2bp,
    const float* __restrict__ lng, const float* __restrict__ lnb,
    unsigned short* __restrict__ hbf) {
  __shared__ char hbuf[16 * 512];        // h bf16 [16][256] swizzled (8 KB)
  __shared__ char gbuf[16 * 2048];       // g bf16 [16][1024] swizzled (32 KB); x-stage @ stride 1024
  __shared__ char ringbuf[8 * 12288];    // per-wave 3 x 4KB W-tile rings (96 KB)
  __shared__ float red[2][16][8];
  const int tid = threadIdx.x, wid = tid >> 6, lane = tid & 63;
  const int r = lane & 15, hi = lane >> 4;
  const int row0 = blockIdx.x << 4;
  const int colb = wid * 32;
  char* ring = ringbuf + wid * 12288;

#pragma unroll
  for (int i = 0; i < 2; ++i) {
    const int id = tid + i * 512, row = id >> 6, c8 = id & 63;
    bf16x8 v = *reinterpret_cast<const bf16x8*>(xb + (size_t)(row0 + row) * 512 + c8 * 8);
    *reinterpret_cast<bf16x8*>(gbuf + row * 1024 + ((c8 * 16) ^ ((row & 7) << 4))) = v;
  }
  __syncthreads();

  f32x4 hreg[2];

  auto store_hb = [&]() {
#pragma unroll
    for (int cf = 0; cf < 2; ++cf) {
      const int cb = (colb + cf * 16 + r) * 2;
#pragma unroll
      for (int j = 0; j < 4; ++j) {
        const int row = hi * 4 + j;
        *reinterpret_cast<unsigned short*>(hbuf + row * 512 + (cb ^ ((row & 7) << 4))) =
            f2b_rne(hreg[cf][j]);
      }
    }
  };

  auto ln_apply = [&](float gm0, float gm1, float bb0, float bb1) {
    float sum[4], sq[4];
#pragma unroll
    for (int j = 0; j < 4; ++j) {
      const float v0 = hreg[0][j], v1 = hreg[1][j];
      sum[j] = v0 + v1; sq[j] = v0 * v0 + v1 * v1;
    }
#pragma unroll
    for (int m = 1; m < 16; m <<= 1)
#pragma unroll
      for (int j = 0; j < 4; ++j) {
        sum[j] += __shfl_xor(sum[j], m, 64);
        sq[j]  += __shfl_xor(sq[j],  m, 64);
      }
    if (r == 0)
#pragma unroll
      for (int j = 0; j < 4; ++j) {
        red[0][hi * 4 + j][wid] = sum[j];
        red[1][hi * 4 + j][wid] = sq[j];
      }
    __syncthreads();
#pragma unroll
    for (int j = 0; j < 4; ++j) {
      const int row = hi * 4 + j;
      f32x4 p0 = *reinterpret_cast<const f32x4*>(&red[0][row][0]);
      f32x4 p1 = *reinterpret_cast<const f32x4*>(&red[0][row][4]);
      f32x4 q0 = *reinterpret_cast<const f32x4*>(&red[1][row][0]);
      f32x4 q1 = *reinterpret_cast<const f32x4*>(&red[1][row][4]);
      const float ts = p0[0]+p0[1]+p0[2]+p0[3]+p1[0]+p1[1]+p1[2]+p1[3];
      const float tq = q0[0]+q0[1]+q0[2]+q0[3]+q1[0]+q1[1]+q1[2]+q1[3];
      const float mean = ts * (1.f / 256.f);
      const float rstd = rsqrtf(tq * (1.f / 256.f) - mean * mean + 1e-5f);
      hreg[0][j] = (hreg[0][j] - mean) * rstd * gm0 + bb0;
      hreg[1][j] = (hreg[1][j] - mean) * rstd * gm1 + bb1;
    }
  };

  {
    f32x4 acc[2] = {};
    gemm_pipe<2, 4, 1024, 512>(pWb, colb, gbuf, ring, lane, acc);
    const float bv0 = projb[colb + r], bv1 = projb[colb + 16 + r];
#pragma unroll
    for (int j = 0; j < 4; ++j) { hreg[0][j] = acc[0][j] + bv0; hreg[1][j] = acc[1][j] + bv1; }
  }
  store_hb();
  __syncthreads();

  for (int L = 0; L < 6; ++L) {
    const float gm0 = lng[L * 256 + colb + r],      gm1 = lng[L * 256 + colb + 16 + r];
    const float bb0 = lnb[L * 256 + colb + r],      bb1 = lnb[L * 256 + colb + 16 + r];
    {
      f32x4 acc[2] = {};
      gemm_pipe<2, 2, 512, 256>(wEff + (size_t)L * 65536, colb, hbuf, ring, lane, acc);
      const float be0 = bEff[L * 256 + colb + r], be1 = bEff[L * 256 + colb + 16 + r];
#pragma unroll
      for (int j = 0; j < 4; ++j) { hreg[0][j] += acc[0][j] + be0; hreg[1][j] += acc[1][j] + be1; }
    }
    ln_apply(gm0, gm1, bb0, bb1);
    store_hb();
    __syncthreads();
    {
      f32x4 accf[8] = {};
      gemm_pipe<8, 2, 512, 256>(f1Wb + (size_t)L * 262144, wid * 128, hbuf, ring, lane, accf);
#pragma unroll
      for (int cf = 0; cf < 8; ++cf) {
        const int colw = wid * 128 + cf * 16 + r;
        const float bv = f1b[L * 1024 + colw];
        const int cb = colw * 2;
#pragma unroll
        for (int j = 0; j < 4; ++j) {
          float y = accf[cf][j] + bv;
          y = 0.5f * y * (1.f + erff(y * 0.70710678118654752f));
          const int row = hi * 4 + j;
          *reinterpret_cast<unsigned short*>(gbuf + row * 2048 + (cb ^ ((row & 7) << 4))) = f2b_rne(y);
        }
      }
    }
    __syncthreads();
    {
      f32x4 acc[2] = {};
      gemm_pipe<2, 8, 2048, 1024>(f2Wb + (size_t)L * 262144, colb, gbuf, ring, lane, acc);
      const float be0 = f2bp[L * 256 + colb + r], be1 = f2bp[L * 256 + colb + 16 + r];
#pragma unroll
      for (int j = 0; j < 4; ++j) { hreg[0][j] += acc[0][j] + be0; hreg[1][j] += acc[1][j] + be1; }
    }
    ln_apply(gm0, gm1, bb0, bb1);
    store_hb();
    __syncthreads();
  }

  {
    f32x4 acc[2] = {};
    gemm_pipe<2, 2, 512, 256>(wEff + 6ull * 65536, colb, hbuf, ring, lane, acc);
    const float be0 = bEff[1536 + colb + r], be1 = bEff[1536 + colb + 16 + r];
#pragma unroll
    for (int j = 0; j < 4; ++j) { hreg[0][j] += acc[0][j] + be0; hreg[1][j] += acc[1][j] + be1; }
  }
#pragma unroll
  for (int cf = 0; cf < 2; ++cf)
#pragma unroll
    for (int j = 0; j < 4; ++j)
      hbf[(size_t)(row0 + hi * 4 + j) * 256 + colb + cf * 16 + r] = f2b_rne(hreg[cf][j]);
}

// ---------------- phase D v4b: (512,2) = 128-VGPR budget, t1 in registers via shuffle ----------------
// grid 6784 = 8 * 848; wg -> (token t, part p) with XCD pairing. 8 waves; wave owns 32 rows.
// LDS: W1s 64KB + consts 1.5KB -> 2 blocks/CU. Swapped GEMM1 -> LN(fold) -> relu -> pack
// in-lane -> shuffle to B-frag -> GEMM2 (W2 from L2) -> dot(w3).
__global__ __launch_bounds__(512, 2) void phase_d4(
    const unsigned short* __restrict__ hbf, const unsigned short* __restrict__ w1b,
    const float* __restrict__ b1, const float* __restrict__ lng, const float* __restrict__ lnb,
    const unsigned short* __restrict__ w2b, const float* __restrict__ b2,
    const float* __restrict__ w3, const float* __restrict__ b3,
    float* __restrict__ out) {
  __shared__ char sm[65536 + 1536];
  const int tid = threadIdx.x, wid = tid >> 6, lane = tid & 63;
  const int r = lane & 15, hi = lane >> 4;
  const int sw = (r & 7) << 4;

  const int wg = blockIdx.x;
  const int pp = wg / 848, rem = wg % 848;
  const int t = rem >> 1;
  const int part = pp * 2 + (rem & 1);           // 0..15
  const int B0 = part * 256 + wid * 32;          // wave's 32 batch rows

  // ---- stage W1 [128][256] swizzled into LDS; consts b1|g|beta (384 f32) ----
  const unsigned short* w1t = w1b + (size_t)t * 32768;
#pragma unroll
  for (int i = 0; i < 8; ++i) {
    const int id = tid + i * 512;
    const int c = id >> 5, s = id & 31;
    bf16x8 v = *reinterpret_cast<const bf16x8*>(w1t + c * 256 + s * 8);
    *reinterpret_cast<bf16x8*>(sm + c * 512 + ((s * 16) ^ ((c & 7) << 4))) = v;
  }
  if (tid < 384) {
    float v;
    if (tid < 128)      v = b1 [t * 128 + tid];
    else if (tid < 256) v = lng[t * 128 + tid - 128];
    else                v = lnb[t * 128 + tid - 256];
    reinterpret_cast<float*>(sm + 65536)[tid] = v;
  }
  __syncthreads();

  const float* cb1 = reinterpret_cast<const float*>(sm + 65536);
  const float* cg  = cb1 + 128;
  const float* cbe = cb1 + 256;

  // ---- GEMM1 (swapped): acc1[cf][bf] = W1 @ h^T ----
  f32x4 acc1[8][2] = {};
  {
    bf16x8 bc[2], bn[2];
#pragma unroll
    for (int bf = 0; bf < 2; ++bf)
      bc[bf] = *reinterpret_cast<const bf16x8*>(hbf + (size_t)(B0 + bf * 16 + r) * 256 + hi * 8);
#pragma unroll
    for (int ks = 0; ks < 8; ++ks) {
      bf16x8 a[8];
#pragma unroll
      for (int cf = 0; cf < 8; ++cf)
        a[cf] = *reinterpret_cast<const bf16x8*>(sm + (cf * 16 + r) * 512 + ((ks * 64 + hi * 16) ^ sw));
      if (ks < 7) {
#pragma unroll
        for (int bf = 0; bf < 2; ++bf)
          bn[bf] = *reinterpret_cast<const bf16x8*>(hbf + (size_t)(B0 + bf * 16 + r) * 256 + (ks + 1) * 32 + hi * 8);
      }
#pragma unroll
      for (int cf = 0; cf < 8; ++cf)
#pragma unroll
        for (int bf = 0; bf < 2; ++bf)
          acc1[cf][bf] = mfma16(a[cf], bc[bf], acc1[cf][bf]);
#pragma unroll
      for (int bf = 0; bf < 2; ++bf) bc[bf] = bn[bf];
    }
  }

  // ---- + b1, LN stats (mean/rstd per row over 128 cols) ----
#pragma unroll
  for (int cf = 0; cf < 8; ++cf) {
    f32x4 b1v = *reinterpret_cast<const f32x4*>(cb1 + cf * 16 + hi * 4);
#pragma unroll
    for (int bf = 0; bf < 2; ++bf) acc1[cf][bf] += b1v;
  }
  float mu[2], rsd[2];
#pragma unroll
  for (int bf = 0; bf < 2; ++bf) {
    float s = 0.f, s2 = 0.f;
#pragma unroll
    for (int cf = 0; cf < 8; ++cf)
#pragma unroll
      for (int j = 0; j < 4; ++j) { float v = acc1[cf][bf][j]; s += v; s2 += v * v; }
    s  += __shfl_xor(s, 16, 64);  s  += __shfl_xor(s, 32, 64);
    s2 += __shfl_xor(s2, 16, 64); s2 += __shfl_xor(s2, 32, 64);
    const float m = s * (1.f / 128.f);
    mu[bf] = m;
    rsd[bf] = rsqrtf(s2 * (1.f / 128.f) - m * m + 1e-5f);
  }

  // ---- LN apply (folded fma) + relu + pack in-lane: pk01/pk23[cf][bf] ----
  unsigned pk01[8][2], pk23[8][2];
#pragma unroll
  for (int cf = 0; cf < 8; ++cf) {
    f32x4 gv = *reinterpret_cast<const f32x4*>(cg  + cf * 16 + hi * 4);
    f32x4 bv = *reinterpret_cast<const f32x4*>(cbe + cf * 16 + hi * 4);
#pragma unroll
    for (int bf = 0; bf < 2; ++bf) {
      f32x4 a4, d4;
#pragma unroll
      for (int j = 0; j < 4; ++j) { a4[j] = gv[j] * rsd[bf]; d4[j] = bv[j] - mu[bf] * a4[j]; }
      float y0 = fmaxf(acc1[cf][bf][0] * a4[0] + d4[0], 0.f);
      float y1 = fmaxf(acc1[cf][bf][1] * a4[1] + d4[1], 0.f);
      float y2 = fmaxf(acc1[cf][bf][2] * a4[2] + d4[2], 0.f);
      float y3 = fmaxf(acc1[cf][bf][3] * a4[3] + d4[3], 0.f);
      pk01[cf][bf] = (unsigned)f2b_rne(y0) | ((unsigned)f2b_rne(y1) << 16);
      pk23[cf][bf] = (unsigned)f2b_rne(y2) | ((unsigned)f2b_rne(y3) << 16);
    }
  }

  // ---- GEMM2: acc2[cf2][bf] += W2frag @ t1frag; t1frag via shuffle transpose ----
  const unsigned short* w2t = w2b + (size_t)t * 8192;   // [64][128]
  f32x4 acc2[4][2] = {};
  const int srcA = r + 32 * (lane >> 4 & 1);   // == r + 32*(hi&1)
  const bool lohalf = (hi < 2);
#pragma unroll
  for (int ks = 0; ks < 4; ++ks) {
    bf16x8 a2[4];
#pragma unroll
    for (int cf2 = 0; cf2 < 4; ++cf2)
      a2[cf2] = *reinterpret_cast<const bf16x8*>(w2t + (cf2 * 16 + r) * 128 + ks * 32 + hi * 8);
#pragma unroll
    for (int bf = 0; bf < 2; ++bf) {
      const unsigned s0 = __shfl(pk01[2 * ks][bf], srcA, 64);
      const unsigned s1 = __shfl(pk23[2 * ks][bf], srcA, 64);
      const unsigned s2 = __shfl(pk01[2 * ks][bf], srcA + 16, 64);
      const unsigned s3 = __shfl(pk23[2 * ks][bf], srcA + 16, 64);
      const unsigned t0 = __shfl(pk01[2 * ks + 1][bf], srcA, 64);
      const unsigned t1v = __shfl(pk23[2 * ks + 1][bf], srcA, 64);
      const unsigned t2 = __shfl(pk01[2 * ks + 1][bf], srcA + 16, 64);
      const unsigned t3 = __shfl(pk23[2 * ks + 1][bf], srcA + 16, 64);
      u32x4 bu;
      bu[0] = lohalf ? s0 : t0;
      bu[1] = lohalf ? s1 : t1v;
      bu[2] = lohalf ? s2 : t2;
      bu[3] = lohalf ? s3 : t3;
      const bf16x8 bfrag = __builtin_bit_cast(bf16x8, bu);
#pragma unroll
      for (int cf2 = 0; cf2 < 4; ++cf2)
        acc2[cf2][bf] = mfma16(a2[cf2], bfrag, acc2[cf2][bf]);
    }
  }

  // ---- epilogue: out[b,t] = relu(acc2 + b2) . w3 + b3 ----
  const float b3t = b3[t];
  float s[2] = {0.f, 0.f};
#pragma unroll
  for (int cf2 = 0; cf2 < 4; ++cf2) {
    f32x4 b2v = *reinterpret_cast<const f32x4*>(b2 + t * 64 + cf2 * 16 + hi * 4);
    f32x4 w3v = *reinterpret_cast<const f32x4*>(w3 + t * 64 + cf2 * 16 + hi * 4);
#pragma unroll
    for (int bf = 0; bf < 2; ++bf)
#pragma unroll
      for (int j = 0; j < 4; ++j)
        s[bf] += fmaxf(acc2[cf2][bf][j] + b2v[j], 0.f) * w3v[j];
  }
#pragma unroll
  for (int bf = 0; bf < 2; ++bf) {
    s[bf] += __shfl_xor(s[bf], 16, 64);
    s[bf] += __shfl_xor(s[bf], 32, 64);
    if (hi == 0) out[(size_t)(B0 + bf * 16 + r) * 424 + t] = s[bf] + b3t;
  }
}

// ---------------- host launch ----------------
extern "C" void kernel_launch(void* const* d_in, const int* in_sizes, int n_in,
                              void* d_out, int out_size, void* d_ws, size_t ws_size,
                              hipStream_t stream) {
  const float* x     = (const float*)d_in[0];
  const float* projW = (const float*)d_in[1];
  const float* projb = (const float*)d_in[2];
  const float* aiW   = (const float*)d_in[3];
  const float* aib   = (const float*)d_in[4];
  const float* aoW   = (const float*)d_in[5];
  const float* aob   = (const float*)d_in[6];
  const float* lng   = (const float*)d_in[7];
  const float* lnbp  = (const float*)d_in[8];
  const float* f1W   = (const float*)d_in[9];
  const float* f1b   = (const float*)d_in[10];
  const float* f2W   = (const float*)d_in[11];
  const float* f2bp  = (const float*)d_in[12];
  const float* ciW   = (const float*)d_in[13];
  const float* cib   = (const float*)d_in[14];
  const float* coW   = (const float*)d_in[15];
  const float* cob   = (const float*)d_in[16];
  const float* tpW1  = (const float*)d_in[17];
  const float* tpb1  = (const float*)d_in[18];
  const float* tplng = (const float*)d_in[19];
  const float* tplnb = (const float*)d_in[20];
  const float* tpW2  = (const float*)d_in[21];
  const float* tpb2  = (const float*)d_in[22];
  const float* tpW3  = (const float*)d_in[23];
  const float* tpb3  = (const float*)d_in[24];
  float* out = (float*)d_out;

  char* ws = (char*)d_ws;
  size_t off = 0;
  auto alloc = [&](size_t n) { char* p = ws + off; off = (off + n + 255) & ~(size_t)255; return p; };
  unsigned short* xb   = (unsigned short*)alloc(4096ull * 512 * 2);
  unsigned short* pWb  = (unsigned short*)alloc(256ull * 512 * 2);
  unsigned short* f1Wb = (unsigned short*)alloc(6ull * 1024 * 256 * 2);
  unsigned short* f2Wb = (unsigned short*)alloc(6ull * 256 * 1024 * 2);
  unsigned short* W1b  = (unsigned short*)alloc(424ull * 128 * 256 * 2);
  unsigned short* W2b  = (unsigned short*)alloc(424ull * 64 * 128 * 2);
  unsigned short* wEff = (unsigned short*)alloc(7ull * 256 * 256 * 2);
  float*          bEff = (float*)alloc(7ull * 256 * 4);
  unsigned short* hbf  = (unsigned short*)alloc(4096ull * 256 * 2);

  auto conv = [&](const float* s, unsigned short* d, size_t n) {
    int n4 = (int)(n >> 2);
    f2b_kernel<<<dim3((n4 + 255) / 256), dim3(256), 0, stream>>>(s, d, n4);
  };
  compose_attn<<<dim3(16, 7), dim3(256), 0, stream>>>(aiW, aib, aoW, aob, ciW, cib, coW, cob, wEff, bEff);
  conv(x, xb, 4096ull * 512);
  conv(projW, pWb, 256ull * 512);
  conv(f1W, f1Wb, 6ull * 1024 * 256);
  conv(f2W, f2Wb, 6ull * 256 * 1024);
  conv(tpW1, W1b, 424ull * 128 * 256);
  conv(tpW2, W2b, 424ull * 64 * 128);

  // whole trunk in one launch: 256 blocks x 16 rows (R6-exact)
  trunk_fused<<<dim3(256), dim3(512), 0, stream>>>(
      xb, pWb, projb, wEff, bEff, f1Wb, f1b, f2Wb, f2bp, lng, lnbp, hbf);

  // phase D v4b: 6784 blocks (8 * 848, XCD-paired), 512 threads, (512,2) reg budget
  phase_d4<<<dim3(6784), dim3(512), 0, stream>>>(hbf, W1b, tpb1, tplng, tplnb, W2b, tpb2, tpW3, tpb3, out);
}

// Round 14
// 580.948 us; speedup vs baseline: 1.0763x; 1.0763x over previous
//
#include <hip/hip_runtime.h>
#include <stdint.h>
#include <utility>
#include <type_traits>

// ---------------- types / helpers ----------------
using bf16x8 = __attribute__((ext_vector_type(8))) short;   // 8 x bf16 (4 VGPRs)
using f32x4  = __attribute__((ext_vector_type(4))) float;
using u32x4  = __attribute__((ext_vector_type(4))) unsigned;

__device__ __forceinline__ f32x4 mfma16(bf16x8 a, bf16x8 b, f32x4 c) {
  return __builtin_amdgcn_mfma_f32_16x16x32_bf16(a, b, c, 0, 0, 0);
}

__device__ __forceinline__ unsigned short f2b_rne(float f) {
  union { float f; unsigned u; } v; v.f = f;
  unsigned r = v.u + 0x7fffu + ((v.u >> 16) & 1u);
  return (unsigned short)(r >> 16);
}

__device__ __forceinline__ void gload16(const void* g, void* l) {
  __builtin_amdgcn_global_load_lds(
      (const __attribute__((address_space(1))) void*)g,
      (__attribute__((address_space(3))) void*)l, 16, 0, 0);
}

template<int N> __device__ __forceinline__ void vmwait() {
  if constexpr (N <= 0)      asm volatile("s_waitcnt vmcnt(0)" ::: "memory");
  else if constexpr (N == 4) asm volatile("s_waitcnt vmcnt(4)" ::: "memory");
  else                       asm volatile("s_waitcnt vmcnt(8)" ::: "memory");
}

template<class F, int... Is>
__device__ __forceinline__ void sfor_impl(F&& f, std::integer_sequence<int, Is...>) {
  (f(std::integral_constant<int, Is>{}), ...);
}
template<int N, class F>
__device__ __forceinline__ void sfor(F&& f) {
  sfor_impl(static_cast<F&&>(f), std::make_integer_sequence<int, N>{});
}

// Stage one 16-col x 128-k tile (4 KB) of W[cols][K] into a wave-private LDS slot.
__device__ __forceinline__ void stage_tile(const unsigned short* __restrict__ W, int K,
                                           int col0, int kt, char* slot, int lane) {
#pragma unroll
  for (int i = 0; i < 4; ++i) {
    const int chunk = i * 64 + lane;
    const int ci = chunk >> 4, kc = chunk & 15;
    const unsigned short* src = W + (size_t)(col0 + ci) * K + kt * 128
                                + (((kc * 16) ^ ((ci & 7) << 4)) >> 1);
    gload16(src, slot + i * 1024);   // lane's 16B lands at slot + i*1024 + lane*16
  }
}

// Per-wave pipelined GEMM (R6-exact): acc[cg] += A[16 x K] @ W[(c0..c0+NCG*16) x K]^T
template<int NCG, int NKT, int AS, int K>
__device__ __forceinline__ void gemm_pipe(const unsigned short* __restrict__ W, int c0,
                                          const char* __restrict__ abuf,
                                          char* __restrict__ ring, int lane,
                                          f32x4 (&acc)[NCG]) {
  const int r = lane & 15, hi16 = (lane >> 4) << 4;
  const int swz = (r & 7) << 4;
  constexpr int TILES = NCG * NKT;   // tile t = (kt, cg) = (t / NCG, t % NCG)
  stage_tile(W, K, c0, 0, ring, lane);
  if constexpr (TILES > 1)
    stage_tile(W, K, c0 + (1 % NCG) * 16, 1 / NCG, ring + 4096, lane);
  bf16x8 areg[4];
  sfor<TILES>([&](auto tc) {
    constexpr int t = tc.value;
    constexpr int kt = t / NCG, cg = t % NCG;
    vmwait<((t + 2 <= TILES) ? 4 : 0)>();
    __builtin_amdgcn_sched_barrier(0);
    if constexpr (t + 2 < TILES) {
      constexpr int t2 = t + 2;
      stage_tile(W, K, c0 + (t2 % NCG) * 16, t2 / NCG, ring + (t2 % 3) * 4096, lane);
    }
    const char* slot = ring + (t % 3) * 4096;
#pragma unroll
    for (int ksl = 0; ksl < 4; ++ksl) {
      if constexpr (cg == 0)
        areg[ksl] = *reinterpret_cast<const bf16x8*>(
            abuf + r * AS + ((kt * 256 + ksl * 64 + hi16) ^ swz));
      const bf16x8 b = *reinterpret_cast<const bf16x8*>(
          slot + r * 256 + ((ksl * 64 + hi16) ^ swz));
      acc[cg] = mfma16(areg[ksl], b, acc[cg]);
    }
  });
}

// ---------------- fp32 -> bf16 conversion ----------------
__global__ void f2b_kernel(const float* __restrict__ s, unsigned short* __restrict__ d, int n4) {
  int i = blockIdx.x * 256 + threadIdx.x;
  if (i >= n4) return;
  float4 v = reinterpret_cast<const float4*>(s)[i];
  ushort4 o;
  o.x = f2b_rne(v.x); o.y = f2b_rne(v.y); o.z = f2b_rne(v.z); o.w = f2b_rne(v.w);
  reinterpret_cast<ushort4*>(d)[i] = o;
}

// ---------------- attn/cross weight composition (fp32): W_eff = Wo @ Wv, b_eff = Wo @ bv + bo ----
__global__ __launch_bounds__(256) void compose_attn(
    const float* __restrict__ aiW, const float* __restrict__ aib,
    const float* __restrict__ aoW, const float* __restrict__ aob,
    const float* __restrict__ ciW, const float* __restrict__ cib,
    const float* __restrict__ coW, const float* __restrict__ cob,
    unsigned short* __restrict__ wEff, float* __restrict__ bEff) {
  const int mat = blockIdx.y;
  const float* Wo = (mat < 6) ? aoW + (size_t)mat * 65536 : coW;
  const float* Wv = (mat < 6) ? aiW + (size_t)mat * 196608 + 131072 : ciW + 131072;
  const float* bv = (mat < 6) ? aib + mat * 768 + 512 : cib + 512;
  const float* bo = (mat < 6) ? aob + mat * 256 : cob;
  unsigned short* Wd = wEff + (size_t)mat * 65536;
  const int m = blockIdx.x * 16 + (threadIdx.x >> 4);
  const int k0 = (threadIdx.x & 15) * 16;
  float c[16] = {};
  for (int j = 0; j < 256; ++j) {
    const float a = Wo[m * 256 + j];
    const float* Br = Wv + j * 256 + k0;
#pragma unroll
    for (int kk = 0; kk < 16; ++kk) c[kk] = fmaf(a, Br[kk], c[kk]);
  }
#pragma unroll
  for (int kk = 0; kk < 16; ++kk) Wd[m * 256 + k0 + kk] = f2b_rne(c[kk]);
  if (blockIdx.x == 0) {
    const int mm = threadIdx.x;
    float s = 0.f;
    for (int j = 0; j < 256; ++j) s = fmaf(Wo[mm * 256 + j], bv[j], s);
    bEff[mat * 256 + mm] = s + bo[mm];
  }
}

// ---------------- fused trunk (R6-exact): 8 waves, 3x4KB LDS W-rings ----------------
__global__ __launch_bounds__(512, 2) void trunk_fused(
    const unsigned short* __restrict__ xb, const unsigned short* __restrict__ pWb,
    const float* __restrict__ projb,
    const unsigned short* __restrict__ wEff, const float* __restrict__ bEff,
    const unsigned short* __restrict__ f1Wb, const float* __restrict__ f1b,
    const unsigned short* __restrict__ f2Wb, const float* __restrict__ f2bp,
    const float* __restrict__ lng, const float* __restrict__ lnb,
    unsigned short* __restrict__ hbf) {
  __shared__ char hbuf[16 * 512];        // h bf16 [16][256] swizzled (8 KB)
  __shared__ char gbuf[16 * 2048];       // g bf16 [16][1024] swizzled (32 KB); x-stage @ stride 1024
  __shared__ char ringbuf[8 * 12288];    // per-wave 3 x 4KB W-tile rings (96 KB)
  __shared__ float red[2][16][8];
  const int tid = threadIdx.x, wid = tid >> 6, lane = tid & 63;
  const int r = lane & 15, hi = lane >> 4;
  const int row0 = blockIdx.x << 4;
  const int colb = wid * 32;
  char* ring = ringbuf + wid * 12288;

#pragma unroll
  for (int i = 0; i < 2; ++i) {
    const int id = tid + i * 512, row = id >> 6, c8 = id & 63;
    bf16x8 v = *reinterpret_cast<const bf16x8*>(xb + (size_t)(row0 + row) * 512 + c8 * 8);
    *reinterpret_cast<bf16x8*>(gbuf + row * 1024 + ((c8 * 16) ^ ((row & 7) << 4))) = v;
  }
  __syncthreads();

  f32x4 hreg[2];

  auto store_hb = [&]() {
#pragma unroll
    for (int cf = 0; cf < 2; ++cf) {
      const int cb = (colb + cf * 16 + r) * 2;
#pragma unroll
      for (int j = 0; j < 4; ++j) {
        const int row = hi * 4 + j;
        *reinterpret_cast<unsigned short*>(hbuf + row * 512 + (cb ^ ((row & 7) << 4))) =
            f2b_rne(hreg[cf][j]);
      }
    }
  };

  auto ln_apply = [&](float gm0, float gm1, float bb0, float bb1) {
    float sum[4], sq[4];
#pragma unroll
    for (int j = 0; j < 4; ++j) {
      const float v0 = hreg[0][j], v1 = hreg[1][j];
      sum[j] = v0 + v1; sq[j] = v0 * v0 + v1 * v1;
    }
#pragma unroll
    for (int m = 1; m < 16; m <<= 1)
#pragma unroll
      for (int j = 0; j < 4; ++j) {
        sum[j] += __shfl_xor(sum[j], m, 64);
        sq[j]  += __shfl_xor(sq[j],  m, 64);
      }
    if (r == 0)
#pragma unroll
      for (int j = 0; j < 4; ++j) {
        red[0][hi * 4 + j][wid] = sum[j];
        red[1][hi * 4 + j][wid] = sq[j];
      }
    __syncthreads();
#pragma unroll
    for (int j = 0; j < 4; ++j) {
      const int row = hi * 4 + j;
      f32x4 p0 = *reinterpret_cast<const f32x4*>(&red[0][row][0]);
      f32x4 p1 = *reinterpret_cast<const f32x4*>(&red[0][row][4]);
      f32x4 q0 = *reinterpret_cast<const f32x4*>(&red[1][row][0]);
      f32x4 q1 = *reinterpret_cast<const f32x4*>(&red[1][row][4]);
      const float ts = p0[0]+p0[1]+p0[2]+p0[3]+p1[0]+p1[1]+p1[2]+p1[3];
      const float tq = q0[0]+q0[1]+q0[2]+q0[3]+q1[0]+q1[1]+q1[2]+q1[3];
      const float mean = ts * (1.f / 256.f);
      const float rstd = rsqrtf(tq * (1.f / 256.f) - mean * mean + 1e-5f);
      hreg[0][j] = (hreg[0][j] - mean) * rstd * gm0 + bb0;
      hreg[1][j] = (hreg[1][j] - mean) * rstd * gm1 + bb1;
    }
  };

  {
    f32x4 acc[2] = {};
    gemm_pipe<2, 4, 1024, 512>(pWb, colb, gbuf, ring, lane, acc);
    const float bv0 = projb[colb + r], bv1 = projb[colb + 16 + r];
#pragma unroll
    for (int j = 0; j < 4; ++j) { hreg[0][j] = acc[0][j] + bv0; hreg[1][j] = acc[1][j] + bv1; }
  }
  store_hb();
  __syncthreads();

  for (int L = 0; L < 6; ++L) {
    const float gm0 = lng[L * 256 + colb + r],      gm1 = lng[L * 256 + colb + 16 + r];
    const float bb0 = lnb[L * 256 + colb + r],      bb1 = lnb[L * 256 + colb + 16 + r];
    {
      f32x4 acc[2] = {};
      gemm_pipe<2, 2, 512, 256>(wEff + (size_t)L * 65536, colb, hbuf, ring, lane, acc);
      const float be0 = bEff[L * 256 + colb + r], be1 = bEff[L * 256 + colb + 16 + r];
#pragma unroll
      for (int j = 0; j < 4; ++j) { hreg[0][j] += acc[0][j] + be0; hreg[1][j] += acc[1][j] + be1; }
    }
    ln_apply(gm0, gm1, bb0, bb1);
    store_hb();
    __syncthreads();
    {
      f32x4 accf[8] = {};
      gemm_pipe<8, 2, 512, 256>(f1Wb + (size_t)L * 262144, wid * 128, hbuf, ring, lane, accf);
#pragma unroll
      for (int cf = 0; cf < 8; ++cf) {
        const int colw = wid * 128 + cf * 16 + r;
        const float bv = f1b[L * 1024 + colw];
        const int cb = colw * 2;
#pragma unroll
        for (int j = 0; j < 4; ++j) {
          float y = accf[cf][j] + bv;
          y = 0.5f * y * (1.f + erff(y * 0.70710678118654752f));
          const int row = hi * 4 + j;
          *reinterpret_cast<unsigned short*>(gbuf + row * 2048 + (cb ^ ((row & 7) << 4))) = f2b_rne(y);
        }
      }
    }
    __syncthreads();
    {
      f32x4 acc[2] = {};
      gemm_pipe<2, 8, 2048, 1024>(f2Wb + (size_t)L * 262144, colb, gbuf, ring, lane, acc);
      const float be0 = f2bp[L * 256 + colb + r], be1 = f2bp[L * 256 + colb + 16 + r];
#pragma unroll
      for (int j = 0; j < 4; ++j) { hreg[0][j] += acc[0][j] + be0; hreg[1][j] += acc[1][j] + be1; }
    }
    ln_apply(gm0, gm1, bb0, bb1);
    store_hb();
    __syncthreads();
  }

  {
    f32x4 acc[2] = {};
    gemm_pipe<2, 2, 512, 256>(wEff + 6ull * 65536, colb, hbuf, ring, lane, acc);
    const float be0 = bEff[1536 + colb + r], be1 = bEff[1536 + colb + 16 + r];
#pragma unroll
    for (int j = 0; j < 4; ++j) { hreg[0][j] += acc[0][j] + be0; hreg[1][j] += acc[1][j] + be1; }
  }
#pragma unroll
  for (int cf = 0; cf < 2; ++cf)
#pragma unroll
    for (int j = 0; j < 4; ++j)
      hbf[(size_t)(row0 + hi * 4 + j) * 256 + colb + cf * 16 + r] = f2b_rne(hreg[cf][j]);
}

// ---------------- phase D v5: XCD-grouped swizzle + lazy pack (no spill) ----------------
// grid 6784; id -> c=id&7 (XCD), q=id>>3, part=q&15, t=(q>>4)*8+c (bijective, t<424).
// All 16 parts of token t are temporally adjacent on XCD t%8 -> W1/W2/hbf fetched once.
// 512 threads = 8 waves; wave owns 32 rows. LDS: W1s 64KB + consts 1.5KB (2 blocks/CU).
// Swapped GEMM1 -> LN-fold -> per-ks lazy {pack 2cf + shuffle-transpose + GEMM2 (W2 from L2)}.
__global__ __launch_bounds__(512, 2) void phase_d5(
    const unsigned short* __restrict__ hbf, const unsigned short* __restrict__ w1b,
    const float* __restrict__ b1, const float* __restrict__ lng, const float* __restrict__ lnb,
    const unsigned short* __restrict__ w2b, const float* __restrict__ b2,
    const float* __restrict__ w3, const float* __restrict__ b3,
    float* __restrict__ out) {
  __shared__ char sm[65536 + 1536];
  const int tid = threadIdx.x, wid = tid >> 6, lane = tid & 63;
  const int r = lane & 15, hi = lane >> 4;
  const int sw = (r & 7) << 4;

  const int id = blockIdx.x;
  const int c = id & 7;
  const int q = id >> 3;
  const int part = q & 15;
  const int t = (q >> 4) * 8 + c;
  const int B0 = part * 256 + wid * 32;          // wave's 32 batch rows

  // ---- stage W1 [128][256] swizzled into LDS; consts b1|g|beta (384 f32) ----
  const unsigned short* w1t = w1b + (size_t)t * 32768;
#pragma unroll
  for (int i = 0; i < 8; ++i) {
    const int iid = tid + i * 512;
    const int cc = iid >> 5, s = iid & 31;
    bf16x8 v = *reinterpret_cast<const bf16x8*>(w1t + cc * 256 + s * 8);
    *reinterpret_cast<bf16x8*>(sm + cc * 512 + ((s * 16) ^ ((cc & 7) << 4))) = v;
  }
  if (tid < 384) {
    float v;
    if (tid < 128)      v = b1 [t * 128 + tid];
    else if (tid < 256) v = lng[t * 128 + tid - 128];
    else                v = lnb[t * 128 + tid - 256];
    reinterpret_cast<float*>(sm + 65536)[tid] = v;
  }
  __syncthreads();

  const float* cb1 = reinterpret_cast<const float*>(sm + 65536);
  const float* cg  = cb1 + 128;
  const float* cbe = cb1 + 256;

  // ---- GEMM1 (swapped): acc1[cf][bf] = W1 @ h^T ----
  f32x4 acc1[8][2] = {};
  {
    bf16x8 bc[2], bn[2];
#pragma unroll
    for (int bf = 0; bf < 2; ++bf)
      bc[bf] = *reinterpret_cast<const bf16x8*>(hbf + (size_t)(B0 + bf * 16 + r) * 256 + hi * 8);
#pragma unroll
    for (int ks = 0; ks < 8; ++ks) {
      bf16x8 a[8];
#pragma unroll
      for (int cf = 0; cf < 8; ++cf)
        a[cf] = *reinterpret_cast<const bf16x8*>(sm + (cf * 16 + r) * 512 + ((ks * 64 + hi * 16) ^ sw));
      if (ks < 7) {
#pragma unroll
        for (int bf = 0; bf < 2; ++bf)
          bn[bf] = *reinterpret_cast<const bf16x8*>(hbf + (size_t)(B0 + bf * 16 + r) * 256 + (ks + 1) * 32 + hi * 8);
      }
#pragma unroll
      for (int cf = 0; cf < 8; ++cf)
#pragma unroll
        for (int bf = 0; bf < 2; ++bf)
          acc1[cf][bf] = mfma16(a[cf], bc[bf], acc1[cf][bf]);
#pragma unroll
      for (int bf = 0; bf < 2; ++bf) bc[bf] = bn[bf];
    }
  }

  // ---- + b1, LN stats (mean/rstd per row over 128 cols) ----
#pragma unroll
  for (int cf = 0; cf < 8; ++cf) {
    f32x4 b1v = *reinterpret_cast<const f32x4*>(cb1 + cf * 16 + hi * 4);
#pragma unroll
    for (int bf = 0; bf < 2; ++bf) acc1[cf][bf] += b1v;
  }
  float mu[2], rsd[2];
#pragma unroll
  for (int bf = 0; bf < 2; ++bf) {
    float s = 0.f, s2 = 0.f;
#pragma unroll
    for (int cf = 0; cf < 8; ++cf)
#pragma unroll
      for (int j = 0; j < 4; ++j) { float v = acc1[cf][bf][j]; s += v; s2 += v * v; }
    s  += __shfl_xor(s, 16, 64);  s  += __shfl_xor(s, 32, 64);
    s2 += __shfl_xor(s2, 16, 64); s2 += __shfl_xor(s2, 32, 64);
    const float m = s * (1.f / 128.f);
    mu[bf] = m;
    rsd[bf] = rsqrtf(s2 * (1.f / 128.f) - m * m + 1e-5f);
  }

  // ---- fused: per ks, lazily pack cf = 2ks, 2ks+1, shuffle-transpose, GEMM2 ----
  const unsigned short* w2t = w2b + (size_t)t * 8192;   // [64][128]
  f32x4 acc2[4][2] = {};
  const int srcA = r + 32 * (hi & 1);
  const bool lohalf = (hi < 2);
#pragma unroll
  for (int ks = 0; ks < 4; ++ks) {
    unsigned pk01[2][2], pk23[2][2];   // [cc = cf - 2ks][bf]
#pragma unroll
    for (int cc = 0; cc < 2; ++cc) {
      const int cf = 2 * ks + cc;
      f32x4 gv = *reinterpret_cast<const f32x4*>(cg  + cf * 16 + hi * 4);
      f32x4 bv = *reinterpret_cast<const f32x4*>(cbe + cf * 16 + hi * 4);
#pragma unroll
      for (int bf = 0; bf < 2; ++bf) {
        f32x4 a4, d4;
#pragma unroll
        for (int j = 0; j < 4; ++j) { a4[j] = gv[j] * rsd[bf]; d4[j] = bv[j] - mu[bf] * a4[j]; }
        float y0 = fmaxf(acc1[cf][bf][0] * a4[0] + d4[0], 0.f);
        float y1 = fmaxf(acc1[cf][bf][1] * a4[1] + d4[1], 0.f);
        float y2 = fmaxf(acc1[cf][bf][2] * a4[2] + d4[2], 0.f);
        float y3 = fmaxf(acc1[cf][bf][3] * a4[3] + d4[3], 0.f);
        pk01[cc][bf] = (unsigned)f2b_rne(y0) | ((unsigned)f2b_rne(y1) << 16);
        pk23[cc][bf] = (unsigned)f2b_rne(y2) | ((unsigned)f2b_rne(y3) << 16);
      }
    }
    bf16x8 a2[4];
#pragma unroll
    for (int cf2 = 0; cf2 < 4; ++cf2)
      a2[cf2] = *reinterpret_cast<const bf16x8*>(w2t + (cf2 * 16 + r) * 128 + ks * 32 + hi * 8);
#pragma unroll
    for (int bf = 0; bf < 2; ++bf) {
      const unsigned s0 = __shfl(pk01[0][bf], srcA, 64);
      const unsigned s1 = __shfl(pk23[0][bf], srcA, 64);
      const unsigned s2 = __shfl(pk01[0][bf], srcA + 16, 64);
      const unsigned s3 = __shfl(pk23[0][bf], srcA + 16, 64);
      const unsigned t0 = __shfl(pk01[1][bf], srcA, 64);
      const unsigned t1v = __shfl(pk23[1][bf], srcA, 64);
      const unsigned t2 = __shfl(pk01[1][bf], srcA + 16, 64);
      const unsigned t3 = __shfl(pk23[1][bf], srcA + 16, 64);
      u32x4 bu;
      bu[0] = lohalf ? s0 : t0;
      bu[1] = lohalf ? s1 : t1v;
      bu[2] = lohalf ? s2 : t2;
      bu[3] = lohalf ? s3 : t3;
      const bf16x8 bfrag = __builtin_bit_cast(bf16x8, bu);
#pragma unroll
      for (int cf2 = 0; cf2 < 4; ++cf2)
        acc2[cf2][bf] = mfma16(a2[cf2], bfrag, acc2[cf2][bf]);
    }
  }

  // ---- epilogue: out[b,t] = relu(acc2 + b2) . w3 + b3 ----
  const float b3t = b3[t];
  float s[2] = {0.f, 0.f};
#pragma unroll
  for (int cf2 = 0; cf2 < 4; ++cf2) {
    f32x4 b2v = *reinterpret_cast<const f32x4*>(b2 + t * 64 + cf2 * 16 + hi * 4);
    f32x4 w3v = *reinterpret_cast<const f32x4*>(w3 + t * 64 + cf2 * 16 + hi * 4);
#pragma unroll
    for (int bf = 0; bf < 2; ++bf)
#pragma unroll
      for (int j = 0; j < 4; ++j)
        s[bf] += fmaxf(acc2[cf2][bf][j] + b2v[j], 0.f) * w3v[j];
  }
#pragma unroll
  for (int bf = 0; bf < 2; ++bf) {
    s[bf] += __shfl_xor(s[bf], 16, 64);
    s[bf] += __shfl_xor(s[bf], 32, 64);
    if (hi == 0) out[(size_t)(B0 + bf * 16 + r) * 424 + t] = s[bf] + b3t;
  }
}

// ---------------- host launch ----------------
extern "C" void kernel_launch(void* const* d_in, const int* in_sizes, int n_in,
                              void* d_out, int out_size, void* d_ws, size_t ws_size,
                              hipStream_t stream) {
  const float* x     = (const float*)d_in[0];
  const float* projW = (const float*)d_in[1];
  const float* projb = (const float*)d_in[2];
  const float* aiW   = (const float*)d_in[3];
  const float* aib   = (const float*)d_in[4];
  const float* aoW   = (const float*)d_in[5];
  const float* aob   = (const float*)d_in[6];
  const float* lng   = (const float*)d_in[7];
  const float* lnbp  = (const float*)d_in[8];
  const float* f1W   = (const float*)d_in[9];
  const float* f1b   = (const float*)d_in[10];
  const float* f2W   = (const float*)d_in[11];
  const float* f2bp  = (const float*)d_in[12];
  const float* ciW   = (const float*)d_in[13];
  const float* cib   = (const float*)d_in[14];
  const float* coW   = (const float*)d_in[15];
  const float* cob   = (const float*)d_in[16];
  const float* tpW1  = (const float*)d_in[17];
  const float* tpb1  = (const float*)d_in[18];
  const float* tplng = (const float*)d_in[19];
  const float* tplnb = (const float*)d_in[20];
  const float* tpW2  = (const float*)d_in[21];
  const float* tpb2  = (const float*)d_in[22];
  const float* tpW3  = (const float*)d_in[23];
  const float* tpb3  = (const float*)d_in[24];
  float* out = (float*)d_out;

  char* ws = (char*)d_ws;
  size_t off = 0;
  auto alloc = [&](size_t n) { char* p = ws + off; off = (off + n + 255) & ~(size_t)255; return p; };
  unsigned short* xb   = (unsigned short*)alloc(4096ull * 512 * 2);
  unsigned short* pWb  = (unsigned short*)alloc(256ull * 512 * 2);
  unsigned short* f1Wb = (unsigned short*)alloc(6ull * 1024 * 256 * 2);
  unsigned short* f2Wb = (unsigned short*)alloc(6ull * 256 * 1024 * 2);
  unsigned short* W1b  = (unsigned short*)alloc(424ull * 128 * 256 * 2);
  unsigned short* W2b  = (unsigned short*)alloc(424ull * 64 * 128 * 2);
  unsigned short* wEff = (unsigned short*)alloc(7ull * 256 * 256 * 2);
  float*          bEff = (float*)alloc(7ull * 256 * 4);
  unsigned short* hbf  = (unsigned short*)alloc(4096ull * 256 * 2);

  auto conv = [&](const float* s, unsigned short* d, size_t n) {
    int n4 = (int)(n >> 2);
    f2b_kernel<<<dim3((n4 + 255) / 256), dim3(256), 0, stream>>>(s, d, n4);
  };
  compose_attn<<<dim3(16, 7), dim3(256), 0, stream>>>(aiW, aib, aoW, aob, ciW, cib, coW, cob, wEff, bEff);
  conv(x, xb, 4096ull * 512);
  conv(projW, pWb, 256ull * 512);
  conv(f1W, f1Wb, 6ull * 1024 * 256);
  conv(f2W, f2Wb, 6ull * 256 * 1024);
  conv(tpW1, W1b, 424ull * 128 * 256);
  conv(tpW2, W2b, 424ull * 64 * 128);

  // whole trunk in one launch: 256 blocks x 16 rows (R6-exact)
  trunk_fused<<<dim3(256), dim3(512), 0, stream>>>(
      xb, pWb, projb, wEff, bEff, f1Wb, f1b, f2Wb, f2bp, lng, lnbp, hbf);

  // phase D v5: 6784 blocks, XCD-grouped bijective swizzle, 512 threads
  phase_d5<<<dim3(6784), dim3(512), 0, stream>>>(hbf, W1b, tpb1, tplng, tplnb, W2b, tpb2, tpW3, tpb3, out);
}